// Round 1
// 280.431 us; speedup vs baseline: 1.1359x; 1.1359x over previous
//
#include <hip/hip_runtime.h>

// BERTEmbedding: out[p, 0:256]   = x[p,0:10] @ W^T + b       (fp32)
//                out[p, 256:512] = sinusoidal PE row doy[p]  (fp32)
// p over B*S = 131072 positions, all fp32.
//
// r4 analysis: previous kernel (1 position per wave) re-loaded each lane's
// W slice (10x float4 @ 160 B inter-lane stride) EVERY position -> ~640
// scattered L1 line transactions per position -> ~137 us of serialized L1
// traffic (matches observed ~153 us kernel time; poison fill is the other
// ~165 us of the 318 us bench figure). Fix: each wave keeps W + PE
// frequency factors in registers and loops over CHUNK=32 consecutive
// positions, amortizing the scattered W load 32x. Per position remains:
// 5 broadcast x-loads + 40 FMA + 4 transcendentals + 2 contiguous float4
// stores -> store-BW-bound (~268 MB out @ ~6.5 TB/s -> ~43 us floor).

#define CHUNK 32

__global__ __launch_bounds__(256) void bert_embed_kernel(
    const float* __restrict__ x,      // [BS, 10]  fp32
    const int*   __restrict__ doy,    // [BS]      int32
    const float* __restrict__ W,      // [256, 10] fp32
    const float* __restrict__ bvec,   // [256]     fp32
    float*       __restrict__ out,    // [BS, 512] fp32
    int BS)
{
    const int lane = threadIdx.x & 63;
    const int wave = threadIdx.x >> 6;
    const int gw   = blockIdx.x * 4 + wave;   // global wave id
    const int base = gw * CHUNK;
    if (base >= BS) return;

    const int d0 = lane * 4;                  // this lane's 4 output dims

    // --- W rows d0..d0+3 (40 floats, 160 B/lane): loaded ONCE per wave,
    //     amortized over CHUNK positions. 16-B aligned. ---
    float wf[40];
    {
        const float4* wp = (const float4*)(W + (size_t)d0 * 10);
        #pragma unroll
        for (int c = 0; c < 10; ++c) {
            float4 v = wp[c];
            wf[4 * c + 0] = v.x; wf[4 * c + 1] = v.y;
            wf[4 * c + 2] = v.z; wf[4 * c + 3] = v.w;
        }
    }

    // --- bias b[d0..d0+3]: one float4, once per wave ---
    const float4 bv = *(const float4*)(bvec + d0);

    // --- PE frequency factors: position-INDEPENDENT, hoisted out of the loop.
    // pe[pos, 2j] = sin(pos * 10000^(-j/128)), pe[pos, 2j+1] = cos(same).
    // rev = angle/(2*pi) = pos * 2^(-j*log2(1e4)/128 - log2(2*pi)) ---
    const float e0 = __builtin_amdgcn_exp2f(
        fmaf((float)(2 * lane + 0), -0.10381025296522976f, -2.651496129472319f));
    const float e1 = __builtin_amdgcn_exp2f(
        fmaf((float)(2 * lane + 1), -0.10381025296522976f, -2.651496129472319f));

    // --- doy for the whole chunk: one coalesced load, broadcast per-iter ---
    int myDoy = 0;
    if (lane < CHUNK && base + lane < BS) myDoy = doy[base + lane];

    const int n = min(CHUNK, BS - base);
    float* o = out + (size_t)base * 512 + d0;

    for (int it = 0; it < n; ++it) {
        const int p = base + it;

        // x[p, 0:10]: wave-uniform row, 40 B, 8-B aligned -> 5 broadcast loads
        const float2* xp = (const float2*)(x + (size_t)p * 10);
        float xf[10];
        #pragma unroll
        for (int c = 0; c < 5; ++c) {
            float2 v = xp[c];
            xf[2 * c]     = v.x;
            xf[2 * c + 1] = v.y;
        }

        // obs_embed: 4 output dims per lane, K=10
        float acc0 = bv.x, acc1 = bv.y, acc2 = bv.z, acc3 = bv.w;
        #pragma unroll
        for (int f = 0; f < 10; ++f) {
            acc0 = fmaf(xf[f], wf[ 0 + f], acc0);
            acc1 = fmaf(xf[f], wf[10 + f], acc1);
            acc2 = fmaf(xf[f], wf[20 + f], acc2);
            acc3 = fmaf(xf[f], wf[30 + f], acc3);
        }

        // PE for this position (broadcast doy via lane shuffle)
        const float pos = (float)__shfl(myDoy, it);
        float r0 = pos * e0;
        float r1 = pos * e1;
        r0 -= floorf(r0);                       // [0,1) revolutions
        r1 -= floorf(r1);
        float4 s1 = { __builtin_amdgcn_sinf(r0), __builtin_amdgcn_cosf(r0),
                      __builtin_amdgcn_sinf(r1), __builtin_amdgcn_cosf(r1) };
        float4 s0 = { acc0, acc1, acc2, acc3 };

        // stores: two float4 per lane; contiguous 2 KB row per position
        *(float4*)(o)       = s0;
        *(float4*)(o + 256) = s1;
        o += 512;
    }
}

extern "C" void kernel_launch(void* const* d_in, const int* in_sizes, int n_in,
                              void* d_out, int out_size, void* d_ws, size_t ws_size,
                              hipStream_t stream) {
    const float* x    = (const float*)d_in[0];
    const int*   doy  = (const int*)d_in[1];
    const float* W    = (const float*)d_in[2];
    const float* bvec = (const float*)d_in[3];
    float*       out  = (float*)d_out;

    const int BS = in_sizes[1];                       // B*S = 131072 positions
    const int waves  = (BS + CHUNK - 1) / CHUNK;      // 1 wave per 32 positions
    const int blocks = (waves + 3) / 4;               // 4 waves per block
    bert_embed_kernel<<<blocks, 256, 0, stream>>>(x, doy, W, bvec, out, BS);
}

// Round 2
// 266.519 us; speedup vs baseline: 1.1952x; 1.0522x over previous
//
#include <hip/hip_runtime.h>

// BERTEmbedding: out[p, 0:256]   = x[p,0:10] @ W^T + b       (fp32)
//                out[p, 256:512] = sinusoidal PE row doy[p]  (fp32)
// p over B*S = 131072 positions, all fp32.
//
// r5: round-1 (CHUNK=32 per wave, per-iter global x loads + __shfl doy) left
// the kernel at ~115 us vs the ~43 us store floor. Theory: per-iteration
// serialized cold x-row HBM misses (vmcnt wait each iter) + ds_bpermute
// lgkm chain. Fix: stage the block's 128 x-rows (5 KB) + 128 doys into LDS
// once via coalesced float4 loads; inner loop reads only LDS (wave-uniform
// broadcast ds_read, no bank conflicts), then 40 FMA + 4 trans + two
// contiguous float4 stores per position. Store-BW-bound target ~43 us.

#define CHUNK  32    // positions per wave
#define BLKPOS 128   // positions per block (4 waves)

__global__ __launch_bounds__(256) void bert_embed_kernel(
    const float* __restrict__ x,      // [BS, 10]  fp32
    const int*   __restrict__ doy,    // [BS]      int32
    const float* __restrict__ W,      // [256, 10] fp32
    const float* __restrict__ bvec,   // [256]     fp32
    float*       __restrict__ out,    // [BS, 512] fp32
    int BS)
{
    __shared__ float lx[BLKPOS * 10];   // 5120 B: x rows for this block
    __shared__ float ldoyf[BLKPOS];     //  512 B: doy as float

    const int tid  = threadIdx.x;
    const int lane = tid & 63;
    const int wave = tid >> 6;
    const int blk_base = blockIdx.x * BLKPOS;
    if (blk_base >= BS) return;

    const int valid = min(BLKPOS, BS - blk_base);

    // --- stage x block into LDS: coalesced float4 (5120 B = 320 float4) ---
    if (valid == BLKPOS) {
        const float4* xb  = (const float4*)(x + (size_t)blk_base * 10); // 16B-aligned: blk_base*40 % 16 == 0
        float4*       lx4 = (float4*)lx;
        int idx = tid;
        lx4[idx] = xb[idx];                 // 256 of 320
        idx += 256;
        if (idx < 320) lx4[idx] = xb[idx];  // remaining 64
    } else {
        for (int i = tid; i < valid * 10; i += 256)
            lx[i] = x[(size_t)blk_base * 10 + i];
    }
    if (tid < valid) ldoyf[tid] = (float)doy[blk_base + tid];

    // --- per-lane W slice: 40 floats, loaded once (overlaps LDS staging) ---
    const int d0 = lane * 4;
    float wf[40];
    {
        const float4* wp = (const float4*)(W + (size_t)d0 * 10);
        #pragma unroll
        for (int c = 0; c < 10; ++c) {
            float4 v = wp[c];
            wf[4 * c + 0] = v.x; wf[4 * c + 1] = v.y;
            wf[4 * c + 2] = v.z; wf[4 * c + 3] = v.w;
        }
    }
    const float4 bv = *(const float4*)(bvec + d0);

    // --- PE frequency factors (position-independent, hoisted) ---
    // pe[pos,2j]=sin(pos*10000^(-j/128)); rev = pos * 2^(-j*log2(1e4)/128 - log2(2pi))
    const float e0 = __builtin_amdgcn_exp2f(
        fmaf((float)(2 * lane + 0), -0.10381025296522976f, -2.651496129472319f));
    const float e1 = __builtin_amdgcn_exp2f(
        fmaf((float)(2 * lane + 1), -0.10381025296522976f, -2.651496129472319f));

    __syncthreads();

    const int wbase = wave * CHUNK;                  // first row (in block) for this wave
    const int n = min(CHUNK, valid - wbase);
    float* o = out + ((size_t)blk_base + wbase) * 512 + d0;

    #pragma unroll 2
    for (int it = 0; it < n; ++it) {
        // x row: wave-uniform LDS address -> broadcast ds_read_b64 x5
        const float* xr = lx + (wbase + it) * 10;    // 40B-aligned
        float xf[10];
        #pragma unroll
        for (int c = 0; c < 5; ++c) {
            float2 v = *(const float2*)(xr + 2 * c);
            xf[2 * c]     = v.x;
            xf[2 * c + 1] = v.y;
        }
        const float pos = ldoyf[wbase + it];         // broadcast ds_read_b32

        // obs_embed: 4 output dims per lane, K=10
        float acc0 = bv.x, acc1 = bv.y, acc2 = bv.z, acc3 = bv.w;
        #pragma unroll
        for (int f = 0; f < 10; ++f) {
            acc0 = fmaf(xf[f], wf[ 0 + f], acc0);
            acc1 = fmaf(xf[f], wf[10 + f], acc1);
            acc2 = fmaf(xf[f], wf[20 + f], acc2);
            acc3 = fmaf(xf[f], wf[30 + f], acc3);
        }

        // PE
        float r0 = pos * e0;
        float r1 = pos * e1;
        r0 -= floorf(r0);                            // [0,1) revolutions
        r1 -= floorf(r1);
        float4 s1 = { __builtin_amdgcn_sinf(r0), __builtin_amdgcn_cosf(r0),
                      __builtin_amdgcn_sinf(r1), __builtin_amdgcn_cosf(r1) };
        float4 s0 = { acc0, acc1, acc2, acc3 };

        // stores: contiguous 1 KB per wave-inst, 2 KB per position
        *(float4*)(o)       = s0;
        *(float4*)(o + 256) = s1;
        o += 512;
    }
}

extern "C" void kernel_launch(void* const* d_in, const int* in_sizes, int n_in,
                              void* d_out, int out_size, void* d_ws, size_t ws_size,
                              hipStream_t stream) {
    const float* x    = (const float*)d_in[0];
    const int*   doy  = (const int*)d_in[1];
    const float* W    = (const float*)d_in[2];
    const float* bvec = (const float*)d_in[3];
    float*       out  = (float*)d_out;

    const int BS = in_sizes[1];                         // B*S = 131072 positions
    const int blocks = (BS + BLKPOS - 1) / BLKPOS;      // 128 positions per block
    bert_embed_kernel<<<blocks, 256, 0, stream>>>(x, doy, W, bvec, out, BS);
}